// Round 1
// baseline (92.964 us; speedup 1.0000x reference)
//
#include <hip/hip_runtime.h>
#include <math.h>

// Problem constants (match reference)
static constexpr int   kC   = 1000;    // NUM_CLASSES
static constexpr int   kD   = 256;     // EMBED_DIM
static constexpr float kMom = 0.995f;  // MOMENTUM
static constexpr float kEps = 1e-12f;  // F.normalize eps

// ---- block-wide sum over 256 threads (4 waves of 64) ----
__device__ __forceinline__ float block_sum256(float v) {
    __shared__ float lds[4];
    #pragma unroll
    for (int off = 32; off > 0; off >>= 1) v += __shfl_down(v, off, 64);
    __syncthreads();                       // protect lds from prior use
    if ((threadIdx.x & 63) == 0) lds[threadIdx.x >> 6] = v;
    __syncthreads();
    return lds[0] + lds[1] + lds[2] + lds[3];
}

// ---- pass 1: per-class counts ----
__global__ void k_hist(const int* __restrict__ labels, int n, int* __restrict__ counts) {
    int i = blockIdx.x * blockDim.x + threadIdx.x;
    if (i < n) atomicAdd(&counts[labels[i]], 1);
}

// ---- pass 2: exclusive scan over counts (single block, C<=1024) ----
__global__ void k_scan(const int* __restrict__ counts,
                       int* __restrict__ starts, int* __restrict__ cursor) {
    __shared__ int buf[1024];
    int t = threadIdx.x;
    int v = (t < kC) ? counts[t] : 0;
    buf[t] = v;
    __syncthreads();
    for (int off = 1; off < 1024; off <<= 1) {
        int add = (t >= off) ? buf[t - off] : 0;
        __syncthreads();
        buf[t] += add;
        __syncthreads();
    }
    if (t < kC) {
        int ex = buf[t] - v;   // exclusive prefix
        starts[t] = ex;
        cursor[t] = ex;
    }
}

// ---- pass 3: scatter row indices into class-sorted order ----
__global__ void k_scatter(const int* __restrict__ labels, int n,
                          int* __restrict__ cursor, int* __restrict__ idx) {
    int i = blockIdx.x * blockDim.x + threadIdx.x;
    if (i < n) {
        int p = atomicAdd(&cursor[labels[i]], 1);
        idx[p] = i;
    }
}

// ---- pass 4: per-class gather-sum + fused normalize/EMA epilogue ----
// one block per class, one thread per embedding dim
__global__ void k_reduce_finalize(const float* __restrict__ z,
                                  const float* __restrict__ protos,
                                  const int* __restrict__ initialized,
                                  const int* __restrict__ counts,
                                  const int* __restrict__ starts,
                                  const int* __restrict__ idx,
                                  float* __restrict__ out) {
    int c = blockIdx.x;
    int d = threadIdx.x;
    int cnt   = counts[c];
    int start = starts[c];

    float sum = 0.0f;
    int r = 0;
    // unroll x4: independent gathered row loads to hide HBM latency
    for (; r + 4 <= cnt; r += 4) {
        int i0 = idx[start + r + 0];
        int i1 = idx[start + r + 1];
        int i2 = idx[start + r + 2];
        int i3 = idx[start + r + 3];
        float a0 = z[i0 * kD + d];
        float a1 = z[i1 * kD + d];
        float a2 = z[i2 * kD + d];
        float a3 = z[i3 * kD + d];
        sum += (a0 + a1) + (a2 + a3);
    }
    for (; r < cnt; ++r) sum += z[idx[start + r] * kD + d];

    float mean  = sum / fmaxf((float)cnt, 1.0f);
    float nrm   = sqrtf(block_sum256(mean * mean));
    float mean_n = mean / fmaxf(nrm, kEps);

    float p   = protos[c * kD + d];
    float e   = kMom * p + (1.0f - kMom) * mean_n;
    float nrm2 = sqrtf(block_sum256(e * e));
    float ema = e / fmaxf(nrm2, kEps);

    float cand = (initialized[c] != 0) ? ema : mean_n;
    out[c * kD + d] = (cnt > 0) ? cand : p;
}

// ---- fallback path (tiny ws): atomic scatter-add into d_out as sums ----
__global__ void k_atomic_accum(const float* __restrict__ z,
                               const int* __restrict__ labels, int n,
                               float* __restrict__ sums, int* __restrict__ counts) {
    int i = blockIdx.x;
    int d = threadIdx.x;
    if (i >= n) return;
    int lab = labels[i];
    atomicAdd(&sums[lab * kD + d], z[i * kD + d]);
    if (d == 0) atomicAdd(&counts[lab], 1);
}

__global__ void k_finalize_from_sums(const float* __restrict__ protos,
                                     const int* __restrict__ initialized,
                                     const int* __restrict__ counts,
                                     float* __restrict__ out) {
    int c = blockIdx.x;
    int d = threadIdx.x;
    int cnt = counts[c];
    float sum = out[c * kD + d];

    float mean  = sum / fmaxf((float)cnt, 1.0f);
    float nrm   = sqrtf(block_sum256(mean * mean));
    float mean_n = mean / fmaxf(nrm, kEps);

    float p   = protos[c * kD + d];
    float e   = kMom * p + (1.0f - kMom) * mean_n;
    float nrm2 = sqrtf(block_sum256(e * e));
    float ema = e / fmaxf(nrm2, kEps);

    float cand = (initialized[c] != 0) ? ema : mean_n;
    out[c * kD + d] = (cnt > 0) ? cand : p;
}

extern "C" void kernel_launch(void* const* d_in, const int* in_sizes, int n_in,
                              void* d_out, int out_size, void* d_ws, size_t ws_size,
                              hipStream_t stream) {
    const float* z           = (const float*)d_in[0];
    const float* protos      = (const float*)d_in[1];
    const int*   initialized = (const int*)d_in[2];
    const int*   labels      = (const int*)d_in[3];
    int n = in_sizes[3];               // N = 131072 (labels count)
    float* out = (float*)d_out;

    int* ws = (int*)d_ws;
    size_t need = (size_t)(3 * 1024 + n) * sizeof(int);

    if (ws_size >= need) {
        int* counts = ws;              // [1000]
        int* starts = ws + 1024;       // [1000]
        int* cursor = ws + 2048;       // [1000]
        int* idx    = ws + 3072;       // [N]
        hipMemsetAsync(counts, 0, kC * sizeof(int), stream);
        int blocks = (n + 255) / 256;
        k_hist   <<<blocks, 256, 0, stream>>>(labels, n, counts);
        k_scan   <<<1, 1024, 0, stream>>>(counts, starts, cursor);
        k_scatter<<<blocks, 256, 0, stream>>>(labels, n, cursor, idx);
        k_reduce_finalize<<<kC, kD, 0, stream>>>(z, protos, initialized,
                                                 counts, starts, idx, out);
    } else {
        // fallback: accumulate sums directly in d_out with float atomics
        int* counts = ws;              // needs only 4 KB
        hipMemsetAsync(counts, 0, kC * sizeof(int), stream);
        hipMemsetAsync(out, 0, (size_t)kC * kD * sizeof(float), stream);
        k_atomic_accum<<<n, kD, 0, stream>>>(z, labels, n, out, counts);
        k_finalize_from_sums<<<kC, kD, 0, stream>>>(protos, initialized, counts, out);
    }
}